// Round 2
// baseline (202.465 us; speedup 1.0000x reference)
//
#include <hip/hip_runtime.h>
#include <hip/hip_bf16.h>

// Problem constants
#define M_TOK 4928   // B*T = 64*77
#define M_PAD 4992   // 39 * 128
#define D_DIM 768
#define NR    4096   // N*R = 1024*4
#define K_CAT 4864   // NR + D_DIM (concat-K for gemm2)

typedef __bf16 bf16;
typedef __attribute__((ext_vector_type(8))) __bf16 bf16x8;
typedef __attribute__((ext_vector_type(4))) float f32x4;
typedef __attribute__((address_space(1))) uint32_t gu32;
typedef __attribute__((address_space(3))) uint32_t su32;

__device__ __forceinline__ float gelu_exact(float v) {
  return 0.5f * v * (1.0f + erff(v * 0.70710678118654752440f));
}

// ---------------- prep kernels ----------------

// x fp32 [4928,768] -> Xb bf16 [4992,768], rows >= 4928 zeroed
__global__ __launch_bounds__(256) void k_prep_x(const float* __restrict__ x,
                                                bf16* __restrict__ Xb) {
  int idx = (blockIdx.x * 256 + threadIdx.x) * 4;
  if (idx >= M_PAD * D_DIM) return;
  int m = idx / D_DIM;
  union { uint2 u; bf16 h[4]; } o;
  if (m < M_TOK) {
    float4 v = *(const float4*)(x + idx);
    o.h[0] = (bf16)v.x; o.h[1] = (bf16)v.y; o.h[2] = (bf16)v.z; o.h[3] = (bf16)v.w;
  } else {
    o.h[0] = o.h[1] = o.h[2] = o.h[3] = (bf16)0.0f;
  }
  *(uint2*)(Xb + idx) = o.u;
}

// w1 fp32 [N=1024][D=768][R=4] -> W1t bf16 [4096 j][768 d] (K-major), j = n*4+r
__global__ __launch_bounds__(256) void k_prep_w1t(const float* __restrict__ w1,
                                                  bf16* __restrict__ W1t) {
  int idx = (blockIdx.x * 256 + threadIdx.x) * 4;
  if (idx >= NR * D_DIM) return;
  int j = idx / D_DIM, d0 = idx % D_DIM;
  int n = j >> 2, r = j & 3;
  const float* src = w1 + n * (D_DIM * 4) + r;
  union { uint2 u; bf16 h[4]; } o;
#pragma unroll
  for (int i = 0; i < 4; ++i) o.h[i] = (bf16)src[(d0 + i) * 4];
  *(uint2*)(W1t + idx) = o.u;
}

// W2t bf16 [768 d][4864 k]: k<4096 -> 0.25*w_out[k][d] ; k>=4096 -> W_org[d][k-4096]
__global__ __launch_bounds__(256) void k_prep_w2t(const float* __restrict__ w_out,
                                                  const float* __restrict__ W_org,
                                                  bf16* __restrict__ W2t) {
  int idx = (blockIdx.x * 256 + threadIdx.x) * 4;
  if (idx >= D_DIM * K_CAT) return;
  int d = idx / K_CAT, k0 = idx % K_CAT;
  union { uint2 u; bf16 h[4]; } o;
  if (k0 < NR) {
#pragma unroll
    for (int i = 0; i < 4; ++i) o.h[i] = (bf16)(0.25f * w_out[(k0 + i) * D_DIM + d]);
  } else {
    float4 v = *(const float4*)(W_org + d * D_DIM + (k0 - NR));
    o.h[0] = (bf16)v.x; o.h[1] = (bf16)v.y; o.h[2] = (bf16)v.z; o.h[3] = (bf16)v.w;
  }
  *(uint2*)(W2t + idx) = o.u;
}

// bias_total[d] = b_org[d] + 0.25 * sum_n b_out[n][d]  (deterministic 2-stage)
__global__ __launch_bounds__(256) void k_bias_partial(const float* __restrict__ b_out,
                                                      float* __restrict__ partial) {
  int b = blockIdx.x;  // 32 blocks, 32 n each
  for (int d = threadIdx.x; d < D_DIM; d += 256) {
    float s = 0.0f;
    for (int n = b * 32; n < b * 32 + 32; ++n) s += b_out[n * D_DIM + d];
    partial[b * D_DIM + d] = s;
  }
}

__global__ __launch_bounds__(256) void k_bias_final(const float* __restrict__ partial,
                                                    const float* __restrict__ b_org,
                                                    float* __restrict__ bias_total) {
  int d = blockIdx.x * 256 + threadIdx.x;
  if (d >= D_DIM) return;
  float s = 0.0f;
#pragma unroll
  for (int b = 0; b < 32; ++b) s += partial[b * D_DIM + d];
  bias_total[d] = b_org[d] + 0.25f * s;
}

// ---------------- GEMM machinery ----------------

// Stage ROWS x 32 bf16 tile (K-contiguous rows of 64B) into linear LDS via
// global_load_lds width 16. Chunk = 16 rows = 1024B, one wave-inst each.
template <int ROWS>
__device__ __forceinline__ void stage_tile(const bf16* g, int ld, int row0, int col0,
                                           bf16* lds) {
  const int lane = threadIdx.x & 63;
  const int wave = threadIdx.x >> 6;
  constexpr int PW = ROWS / 64;  // chunks per wave
#pragma unroll
  for (int c = 0; c < PW; ++c) {
    const int chunk = wave * PW + c;
    const int row = row0 + chunk * 16 + (lane >> 2);
    const bf16* gp = g + (size_t)row * ld + col0 + ((lane & 3) << 3);
    __builtin_amdgcn_global_load_lds((gu32*)gp, (su32*)(lds + chunk * 512), 16, 0, 0);
  }
}

// GEMM1: Xb[4992,768] x W1t[4096,768]^T-layout -> H2 bf16 [4992,4096]
// epilogue: gelu(acc + b1[j]) * midw_diag[j] + midb[j] -> gelu -> bf16
__global__ __launch_bounds__(256) void k_gemm1(const bf16* __restrict__ Xb,
                                               const bf16* __restrict__ W1t,
                                               bf16* __restrict__ H2,
                                               const float* __restrict__ b1,
                                               const float* __restrict__ midw,
                                               const float* __restrict__ midb) {
  __shared__ bf16 As[128 * 32];
  __shared__ bf16 Bs[128 * 32];
  const int bmt = blockIdx.x >> 5;       // 39 M-tiles
  const int bnt = blockIdx.x & 31;       // 32 N-tiles
  const int m0 = bmt * 128, n0 = bnt * 128;
  const int lane = threadIdx.x & 63;
  const int wave = threadIdx.x >> 6;
  const int wm = wave >> 1, wn = wave & 1;
  const int lr = lane & 15, kg = lane >> 4;

  f32x4 acc[4][4];
#pragma unroll
  for (int i = 0; i < 4; ++i)
#pragma unroll
    for (int j = 0; j < 4; ++j) acc[i][j] = (f32x4)(0.0f);

  for (int kt = 0; kt < 24; ++kt) {
    const int k0 = kt * 32;
    stage_tile<128>(Xb, D_DIM, m0, k0, As);
    stage_tile<128>(W1t, D_DIM, n0, k0, Bs);
    __syncthreads();
    bf16x8 a[4], b[4];
#pragma unroll
    for (int i = 0; i < 4; ++i)
      a[i] = *(const bf16x8*)(As + (wm * 64 + i * 16 + lr) * 32 + kg * 8);
#pragma unroll
    for (int j = 0; j < 4; ++j)
      b[j] = *(const bf16x8*)(Bs + (wn * 64 + j * 16 + lr) * 32 + kg * 8);
#pragma unroll
    for (int i = 0; i < 4; ++i)
#pragma unroll
      for (int j = 0; j < 4; ++j)
        acc[i][j] = __builtin_amdgcn_mfma_f32_16x16x32_bf16(a[i], b[j], acc[i][j], 0, 0, 0);
    __syncthreads();
  }

#pragma unroll
  for (int j = 0; j < 4; ++j) {
    const int col = n0 + wn * 64 + j * 16 + lr;
    const float b1v = b1[col];
    const float mdv = midw[(col >> 2) * 16 + (col & 3) * 5];  // mid_w[n][r][r]
    const float mbv = midb[col];
#pragma unroll
    for (int i = 0; i < 4; ++i) {
      const int r0 = m0 + wm * 64 + i * 16 + kg * 4;
#pragma unroll
      for (int rr = 0; rr < 4; ++rr) {
        float h = acc[i][j][rr] + b1v;
        h = gelu_exact(h);
        h = h * mdv + mbv;
        h = gelu_exact(h);
        H2[(size_t)(r0 + rr) * NR + col] = (bf16)h;
      }
    }
  }
}

// GEMM2: A = [H2 | Xb] (K = 4864) x W2t[768,4864] -> out fp32 [4928,768] + bias
__global__ __launch_bounds__(256) void k_gemm2(const bf16* __restrict__ H2,
                                               const bf16* __restrict__ Xb,
                                               const bf16* __restrict__ W2t,
                                               float* __restrict__ out,
                                               const float* __restrict__ bias) {
  __shared__ bf16 As[128 * 32];
  __shared__ bf16 Bs[64 * 32];
  const int bmt = blockIdx.x / 12;       // 39 M-tiles
  const int bnt = blockIdx.x % 12;       // 12 N-tiles of 64
  const int m0 = bmt * 128, n0 = bnt * 64;
  const int lane = threadIdx.x & 63;
  const int wave = threadIdx.x >> 6;
  const int wm = wave >> 1, wn = wave & 1;
  const int lr = lane & 15, kg = lane >> 4;

  f32x4 acc[4][2];
#pragma unroll
  for (int i = 0; i < 4; ++i)
#pragma unroll
    for (int j = 0; j < 2; ++j) acc[i][j] = (f32x4)(0.0f);

  for (int kt = 0; kt < 152; ++kt) {
    const int k0 = kt * 32;
    if (k0 < NR) stage_tile<128>(H2, NR, m0, k0, As);
    else         stage_tile<128>(Xb, D_DIM, m0, k0 - NR, As);
    stage_tile<64>(W2t, K_CAT, n0, k0, Bs);
    __syncthreads();
    bf16x8 a[4], b[2];
#pragma unroll
    for (int i = 0; i < 4; ++i)
      a[i] = *(const bf16x8*)(As + (wm * 64 + i * 16 + lr) * 32 + kg * 8);
#pragma unroll
    for (int j = 0; j < 2; ++j)
      b[j] = *(const bf16x8*)(Bs + (wn * 32 + j * 16 + lr) * 32 + kg * 8);
#pragma unroll
    for (int i = 0; i < 4; ++i)
#pragma unroll
      for (int j = 0; j < 2; ++j)
        acc[i][j] = __builtin_amdgcn_mfma_f32_16x16x32_bf16(a[i], b[j], acc[i][j], 0, 0, 0);
    __syncthreads();
  }

#pragma unroll
  for (int j = 0; j < 2; ++j) {
    const int col = n0 + wn * 32 + j * 16 + lr;
    const float bv = bias[col];
#pragma unroll
    for (int i = 0; i < 4; ++i) {
      const int r0 = m0 + wm * 64 + i * 16 + kg * 4;
#pragma unroll
      for (int rr = 0; rr < 4; ++rr) {
        const int row = r0 + rr;
        if (row < M_TOK) out[(size_t)row * D_DIM + col] = acc[i][j][rr] + bv;
      }
    }
  }
}

// ---------------- launch ----------------

extern "C" void kernel_launch(void* const* d_in, const int* in_sizes, int n_in,
                              void* d_out, int out_size, void* d_ws, size_t ws_size,
                              hipStream_t stream) {
  const float* x     = (const float*)d_in[0];
  const float* W_org = (const float*)d_in[1];
  const float* b_org = (const float*)d_in[2];
  const float* w1    = (const float*)d_in[3];
  const float* b1    = (const float*)d_in[4];
  const float* mid_w = (const float*)d_in[5];
  const float* mid_b = (const float*)d_in[6];
  const float* w_out = (const float*)d_in[7];
  const float* b_out = (const float*)d_in[8];
  float* out = (float*)d_out;

  // workspace carve-up (~60 MB total)
  bf16* Xb   = (bf16*)d_ws;                         // 4992*768
  bf16* W1t  = Xb  + (size_t)M_PAD * D_DIM;         // 4096*768
  bf16* W2t  = W1t + (size_t)NR * D_DIM;            // 768*4864
  bf16* H2   = W2t + (size_t)D_DIM * K_CAT;         // 4992*4096
  float* bias    = (float*)(H2 + (size_t)M_PAD * NR);
  float* partial = bias + 1024;                     // 32*768 floats

  k_prep_x   <<<(M_PAD * D_DIM / 4) / 256, 256, 0, stream>>>(x, Xb);
  k_prep_w1t <<<(NR * D_DIM / 4) / 256, 256, 0, stream>>>(w1, W1t);
  k_prep_w2t <<<(D_DIM * K_CAT / 4) / 256, 256, 0, stream>>>(w_out, W_org, W2t);
  k_bias_partial<<<32, 256, 0, stream>>>(b_out, partial);
  k_bias_final  <<<3, 256, 0, stream>>>(partial, b_org, bias);

  k_gemm1<<<39 * 32, 256, 0, stream>>>(Xb, W1t, H2, b1, mid_w, mid_b);
  k_gemm2<<<39 * 12, 256, 0, stream>>>(H2, Xb, W2t, out, bias);
}

// Round 3
// 187.330 us; speedup vs baseline: 1.0808x; 1.0808x over previous
//
#include <hip/hip_runtime.h>
#include <hip/hip_bf16.h>

// Problem constants
#define M_TOK 4928   // B*T = 64*77
#define M_PAD 4992   // 39 * 128
#define D_DIM 768
#define NR    4096   // N*R = 1024*4
#define K_CAT 4864   // NR + D_DIM (concat-K for gemm2)
#define KT_ALL 152   // K_CAT / 32

typedef __bf16 bf16;
typedef __attribute__((ext_vector_type(8))) __bf16 bf16x8;
typedef __attribute__((ext_vector_type(4))) float f32x4;
typedef __attribute__((address_space(1))) uint32_t gu32;
typedef __attribute__((address_space(3))) uint32_t su32;

__device__ __forceinline__ float gelu_exact(float v) {
  return 0.5f * v * (1.0f + erff(v * 0.70710678118654752440f));
}

// m204 bijective XCD swizzle: hardware blockIdx -> logical wgid such that
// logically-consecutive blocks land on the same XCD (chunks of ~nwg/8).
__device__ __forceinline__ int xcd_swizzle(int orig, int nwg) {
  const int q = nwg >> 3, r = nwg & 7;
  const int x = orig & 7, rest = orig >> 3;
  return (x < r ? x * (q + 1) : r * (q + 1) + (x - r) * q) + rest;
}

// ---------------- prep kernels ----------------

__global__ __launch_bounds__(256) void k_prep_x(const float* __restrict__ x,
                                                bf16* __restrict__ Xb) {
  int idx = (blockIdx.x * 256 + threadIdx.x) * 4;
  if (idx >= M_PAD * D_DIM) return;
  int m = idx / D_DIM;
  union { uint2 u; bf16 h[4]; } o;
  if (m < M_TOK) {
    float4 v = *(const float4*)(x + idx);
    o.h[0] = (bf16)v.x; o.h[1] = (bf16)v.y; o.h[2] = (bf16)v.z; o.h[3] = (bf16)v.w;
  } else {
    o.h[0] = o.h[1] = o.h[2] = o.h[3] = (bf16)0.0f;
  }
  *(uint2*)(Xb + idx) = o.u;
}

// w1 fp32 [N=1024][D=768][R=4] -> W1t bf16 [4096 j][768 d] (K-major), j = n*4+r
__global__ __launch_bounds__(256) void k_prep_w1t(const float* __restrict__ w1,
                                                  bf16* __restrict__ W1t) {
  int idx = (blockIdx.x * 256 + threadIdx.x) * 4;
  if (idx >= NR * D_DIM) return;
  int j = idx / D_DIM, d0 = idx % D_DIM;
  int n = j >> 2, r = j & 3;
  const float* src = w1 + n * (D_DIM * 4) + r;
  union { uint2 u; bf16 h[4]; } o;
#pragma unroll
  for (int i = 0; i < 4; ++i) o.h[i] = (bf16)src[(d0 + i) * 4];
  *(uint2*)(W1t + idx) = o.u;
}

// W2t bf16 [768 d][4864 k]: k<4096 -> 0.25*w_out[k][d] ; k>=4096 -> W_org[d][k-4096]
__global__ __launch_bounds__(256) void k_prep_w2t(const float* __restrict__ w_out,
                                                  const float* __restrict__ W_org,
                                                  bf16* __restrict__ W2t) {
  int idx = (blockIdx.x * 256 + threadIdx.x) * 4;
  if (idx >= D_DIM * K_CAT) return;
  int d = idx / K_CAT, k0 = idx % K_CAT;
  union { uint2 u; bf16 h[4]; } o;
  if (k0 < NR) {
#pragma unroll
    for (int i = 0; i < 4; ++i) o.h[i] = (bf16)(0.25f * w_out[(k0 + i) * D_DIM + d]);
  } else {
    float4 v = *(const float4*)(W_org + d * D_DIM + (k0 - NR));
    o.h[0] = (bf16)v.x; o.h[1] = (bf16)v.y; o.h[2] = (bf16)v.z; o.h[3] = (bf16)v.w;
  }
  *(uint2*)(W2t + idx) = o.u;
}

// bias_total[d] = b_org[d] + 0.25 * sum_n b_out[n][d]  (deterministic 2-stage)
__global__ __launch_bounds__(256) void k_bias_partial(const float* __restrict__ b_out,
                                                      float* __restrict__ partial) {
  int b = blockIdx.x;
  for (int d = threadIdx.x; d < D_DIM; d += 256) {
    float s = 0.0f;
    for (int n = b * 32; n < b * 32 + 32; ++n) s += b_out[n * D_DIM + d];
    partial[b * D_DIM + d] = s;
  }
}

__global__ __launch_bounds__(256) void k_bias_final(const float* __restrict__ partial,
                                                    const float* __restrict__ b_org,
                                                    float* __restrict__ bias_total) {
  int d = blockIdx.x * 256 + threadIdx.x;
  if (d >= D_DIM) return;
  float s = 0.0f;
#pragma unroll
  for (int b = 0; b < 32; ++b) s += partial[b * D_DIM + d];
  bias_total[d] = b_org[d] + 0.25f * s;
}

// ---------------- GEMM machinery ----------------

// Stage ROWS x 32 bf16 tile (K-contiguous rows of 64B) into linear LDS via
// global_load_lds width 16. Chunk = 16 rows = 1024B, one wave-inst each.
template <int ROWS>
__device__ __forceinline__ void stage_tile(const bf16* g, int ld, int row0, int col0,
                                           bf16* lds) {
  const int lane = threadIdx.x & 63;
  const int wave = threadIdx.x >> 6;
  constexpr int PW = ROWS / 64;  // chunks per wave
#pragma unroll
  for (int c = 0; c < PW; ++c) {
    const int chunk = wave * PW + c;
    const int row = row0 + chunk * 16 + (lane >> 2);
    const bf16* gp = g + (size_t)row * ld + col0 + ((lane & 3) << 3);
    __builtin_amdgcn_global_load_lds((gu32*)gp, (su32*)(lds + chunk * 512), 16, 0, 0);
  }
}

// GEMM1: Xb[4992,768] x W1t[4096,768]^T-layout -> H2 bf16 [4992,4096]
__global__ __launch_bounds__(256) void k_gemm1(const bf16* __restrict__ Xb,
                                               const bf16* __restrict__ W1t,
                                               bf16* __restrict__ H2,
                                               const float* __restrict__ b1,
                                               const float* __restrict__ midw,
                                               const float* __restrict__ midb) {
  __shared__ bf16 As[128 * 32];
  __shared__ bf16 Bs[128 * 32];
  const int wgid = xcd_swizzle(blockIdx.x, 39 * 32);
  const int bmt = wgid >> 5;             // 39 M-tiles
  const int bnt = wgid & 31;             // 32 N-tiles (consecutive share A-panel)
  const int m0 = bmt * 128, n0 = bnt * 128;
  const int lane = threadIdx.x & 63;
  const int wave = threadIdx.x >> 6;
  const int wm = wave >> 1, wn = wave & 1;
  const int lr = lane & 15, kg = lane >> 4;

  f32x4 acc[4][4];
#pragma unroll
  for (int i = 0; i < 4; ++i)
#pragma unroll
    for (int j = 0; j < 4; ++j) acc[i][j] = (f32x4)(0.0f);

  for (int kt = 0; kt < 24; ++kt) {
    const int k0 = kt * 32;
    stage_tile<128>(Xb, D_DIM, m0, k0, As);
    stage_tile<128>(W1t, D_DIM, n0, k0, Bs);
    __syncthreads();
    bf16x8 a[4], b[4];
#pragma unroll
    for (int i = 0; i < 4; ++i)
      a[i] = *(const bf16x8*)(As + (wm * 64 + i * 16 + lr) * 32 + kg * 8);
#pragma unroll
    for (int j = 0; j < 4; ++j)
      b[j] = *(const bf16x8*)(Bs + (wn * 64 + j * 16 + lr) * 32 + kg * 8);
#pragma unroll
    for (int i = 0; i < 4; ++i)
#pragma unroll
      for (int j = 0; j < 4; ++j)
        acc[i][j] = __builtin_amdgcn_mfma_f32_16x16x32_bf16(a[i], b[j], acc[i][j], 0, 0, 0);
    __syncthreads();
  }

#pragma unroll
  for (int j = 0; j < 4; ++j) {
    const int col = n0 + wn * 64 + j * 16 + lr;
    const float b1v = b1[col];
    const float mdv = midw[(col >> 2) * 16 + (col & 3) * 5];  // mid_w[n][r][r]
    const float mbv = midb[col];
#pragma unroll
    for (int i = 0; i < 4; ++i) {
      const int r0 = m0 + wm * 64 + i * 16 + kg * 4;
#pragma unroll
      for (int rr = 0; rr < 4; ++rr) {
        float h = acc[i][j][rr] + b1v;
        h = gelu_exact(h);
        h = h * mdv + mbv;
        h = gelu_exact(h);
        H2[(size_t)(r0 + rr) * NR + col] = (bf16)h;
      }
    }
  }
}

// GEMM2: A = [H2 | Xb] (K = 4864) x W2t[768,4864] -> out/partial
// SPLITS>1: writes fp32 partial (no bias); SPLITS==1: writes out + bias.
template <int SPLITS>
__global__ __launch_bounds__(256) void k_gemm2(const bf16* __restrict__ H2,
                                               const bf16* __restrict__ Xb,
                                               const bf16* __restrict__ W2t,
                                               float* __restrict__ outp,
                                               const float* __restrict__ bias) {
  __shared__ bf16 As[128 * 32];
  __shared__ bf16 Bs[64 * 32];
  const int nwg = 39 * 12 * SPLITS;
  const int wgid = xcd_swizzle(blockIdx.x, nwg);
  const int bmt = wgid / (12 * SPLITS);
  const int rem = wgid % (12 * SPLITS);
  const int ks  = rem / 12;
  const int bnt = rem % 12;              // 12 consecutive share A-panel
  const int m0 = bmt * 128, n0 = bnt * 64;
  const int lane = threadIdx.x & 63;
  const int wave = threadIdx.x >> 6;
  const int wm = wave >> 1, wn = wave & 1;
  const int lr = lane & 15, kg = lane >> 4;
  constexpr int KT_PER = KT_ALL / SPLITS;

  f32x4 acc[4][2];
#pragma unroll
  for (int i = 0; i < 4; ++i)
#pragma unroll
    for (int j = 0; j < 2; ++j) acc[i][j] = (f32x4)(0.0f);

  for (int kt = ks * KT_PER; kt < (ks + 1) * KT_PER; ++kt) {
    const int k0 = kt * 32;
    if (k0 < NR) stage_tile<128>(H2, NR, m0, k0, As);
    else         stage_tile<128>(Xb, D_DIM, m0, k0 - NR, As);
    stage_tile<64>(W2t, K_CAT, n0, k0, Bs);
    __syncthreads();
    bf16x8 a[4], b[2];
#pragma unroll
    for (int i = 0; i < 4; ++i)
      a[i] = *(const bf16x8*)(As + (wm * 64 + i * 16 + lr) * 32 + kg * 8);
#pragma unroll
    for (int j = 0; j < 2; ++j)
      b[j] = *(const bf16x8*)(Bs + (wn * 32 + j * 16 + lr) * 32 + kg * 8);
#pragma unroll
    for (int i = 0; i < 4; ++i)
#pragma unroll
      for (int j = 0; j < 2; ++j)
        acc[i][j] = __builtin_amdgcn_mfma_f32_16x16x32_bf16(a[i], b[j], acc[i][j], 0, 0, 0);
    __syncthreads();
  }

  float* dst = (SPLITS > 1) ? outp + (size_t)ks * M_TOK * D_DIM : outp;
#pragma unroll
  for (int j = 0; j < 2; ++j) {
    const int col = n0 + wn * 32 + j * 16 + lr;
    const float bv = (SPLITS > 1) ? 0.0f : bias[col];
#pragma unroll
    for (int i = 0; i < 4; ++i) {
      const int r0 = m0 + wm * 64 + i * 16 + kg * 4;
#pragma unroll
      for (int rr = 0; rr < 4; ++rr) {
        const int row = r0 + rr;
        if (row < M_TOK) dst[(size_t)row * D_DIM + col] = acc[i][j][rr] + bv;
      }
    }
  }
}

// out = sum_s partial[s] + bias  (vectorized float4)
template <int SPLITS>
__global__ __launch_bounds__(256) void k_reduce(const float* __restrict__ padd,
                                                const float* __restrict__ bias,
                                                float* __restrict__ out) {
  int idx = (blockIdx.x * 256 + threadIdx.x) * 4;
  if (idx >= M_TOK * D_DIM) return;
  float4 s = *(const float4*)(bias + (idx % D_DIM));
#pragma unroll
  for (int p = 0; p < SPLITS; ++p) {
    float4 v = *(const float4*)(padd + (size_t)p * M_TOK * D_DIM + idx);
    s.x += v.x; s.y += v.y; s.z += v.z; s.w += v.w;
  }
  *(float4*)(out + idx) = s;
}

// ---------------- launch ----------------

extern "C" void kernel_launch(void* const* d_in, const int* in_sizes, int n_in,
                              void* d_out, int out_size, void* d_ws, size_t ws_size,
                              hipStream_t stream) {
  const float* x     = (const float*)d_in[0];
  const float* W_org = (const float*)d_in[1];
  const float* b_org = (const float*)d_in[2];
  const float* w1    = (const float*)d_in[3];
  const float* b1    = (const float*)d_in[4];
  const float* mid_w = (const float*)d_in[5];
  const float* mid_b = (const float*)d_in[6];
  const float* w_out = (const float*)d_in[7];
  const float* b_out = (const float*)d_in[8];
  float* out = (float*)d_out;

  // workspace carve-up
  bf16* Xb   = (bf16*)d_ws;                         // 4992*768
  bf16* W1t  = Xb  + (size_t)M_PAD * D_DIM;         // 4096*768
  bf16* W2t  = W1t + (size_t)NR * D_DIM;            // 768*4864
  bf16* H2   = W2t + (size_t)D_DIM * K_CAT;         // 4992*4096
  float* bias    = (float*)(H2 + (size_t)M_PAD * NR);
  float* partial = bias + 1024;                     // 32*768 floats
  float* padd    = partial + 32 * D_DIM;            // SPLITS * 4928*768 floats

  const size_t base_bytes = (size_t)((char*)padd - (char*)d_ws);
  const size_t per_split  = (size_t)M_TOK * D_DIM * sizeof(float);
  int S = 1;
  if (ws_size >= base_bytes + 4 * per_split)      S = 4;
  else if (ws_size >= base_bytes + 2 * per_split) S = 2;

  k_prep_x   <<<(M_PAD * D_DIM / 4) / 256, 256, 0, stream>>>(x, Xb);
  k_prep_w1t <<<(NR * D_DIM / 4) / 256, 256, 0, stream>>>(w1, W1t);
  k_prep_w2t <<<(D_DIM * K_CAT / 4) / 256, 256, 0, stream>>>(w_out, W_org, W2t);
  k_bias_partial<<<32, 256, 0, stream>>>(b_out, partial);
  k_bias_final  <<<3, 256, 0, stream>>>(partial, b_org, bias);

  k_gemm1<<<39 * 32, 256, 0, stream>>>(Xb, W1t, H2, b1, mid_w, mid_b);

  const int red_grid = (M_TOK * D_DIM / 4 + 255) / 256;
  if (S == 4) {
    k_gemm2<4><<<39 * 12 * 4, 256, 0, stream>>>(H2, Xb, W2t, padd, bias);
    k_reduce<4><<<red_grid, 256, 0, stream>>>(padd, bias, out);
  } else if (S == 2) {
    k_gemm2<2><<<39 * 12 * 2, 256, 0, stream>>>(H2, Xb, W2t, padd, bias);
    k_reduce<2><<<red_grid, 256, 0, stream>>>(padd, bias, out);
  } else {
    k_gemm2<1><<<39 * 12, 256, 0, stream>>>(H2, Xb, W2t, out, bias);
  }
}

// Round 4
// 174.451 us; speedup vs baseline: 1.1606x; 1.0738x over previous
//
#include <hip/hip_runtime.h>
#include <hip/hip_bf16.h>

// Problem constants
#define M_TOK 4928   // B*T = 64*77
#define M_PAD 4992   // 39 * 128
#define D_DIM 768
#define NR    4096   // N*R = 1024*4
#define K_CAT 4864   // NR + D_DIM (concat-K for gemm2)
#define KT_ALL 152   // K_CAT / 32

typedef __bf16 bf16;
typedef __attribute__((ext_vector_type(8))) __bf16 bf16x8;
typedef __attribute__((ext_vector_type(4))) float f32x4;
typedef __attribute__((address_space(1))) uint32_t gu32;
typedef __attribute__((address_space(3))) uint32_t su32;

// tanh-form gelu via sigmoid: x * sigmoid(1.5957692*(x + 0.044715 x^3)).
// Max abs error vs exact gelu ~3e-4 -- far under this problem's threshold
// (output dominated by org-path; bf16 rounding already 1.6e-2 vs 5.8e-2 thr).
// ~8 VALU insts vs ~30+ for libm erff (which made gemm1 epilogue-bound).
__device__ __forceinline__ float gelu_fast(float v) {
  float p = v * v;
  float u = v * fmaf(0.07135481283f, p, 1.595769122f);
  float e = __expf(-u);
  return v * __builtin_amdgcn_rcpf(1.0f + e);
}

// m204 bijective XCD swizzle: hardware blockIdx -> logical wgid such that
// logically-consecutive blocks land on the same XCD (chunks of ~nwg/8).
__device__ __forceinline__ int xcd_swizzle(int orig, int nwg) {
  const int q = nwg >> 3, r = nwg & 7;
  const int x = orig & 7, rest = orig >> 3;
  return (x < r ? x * (q + 1) : r * (q + 1) + (x - r) * q) + rest;
}

// ---------------- prep kernels ----------------

__global__ __launch_bounds__(256) void k_prep_x(const float* __restrict__ x,
                                                bf16* __restrict__ Xb) {
  int idx = (blockIdx.x * 256 + threadIdx.x) * 4;
  if (idx >= M_PAD * D_DIM) return;
  int m = idx / D_DIM;
  union { uint2 u; bf16 h[4]; } o;
  if (m < M_TOK) {
    float4 v = *(const float4*)(x + idx);
    o.h[0] = (bf16)v.x; o.h[1] = (bf16)v.y; o.h[2] = (bf16)v.z; o.h[3] = (bf16)v.w;
  } else {
    o.h[0] = o.h[1] = o.h[2] = o.h[3] = (bf16)0.0f;
  }
  *(uint2*)(Xb + idx) = o.u;
}

// w1 fp32 [N=1024][D=768][R=4] -> W1t bf16 [4096 j][768 d] (K-major), j = n*4+r
__global__ __launch_bounds__(256) void k_prep_w1t(const float* __restrict__ w1,
                                                  bf16* __restrict__ W1t) {
  int idx = (blockIdx.x * 256 + threadIdx.x) * 4;
  if (idx >= NR * D_DIM) return;
  int j = idx / D_DIM, d0 = idx % D_DIM;
  int n = j >> 2, r = j & 3;
  const float* src = w1 + n * (D_DIM * 4) + r;
  union { uint2 u; bf16 h[4]; } o;
#pragma unroll
  for (int i = 0; i < 4; ++i) o.h[i] = (bf16)src[(d0 + i) * 4];
  *(uint2*)(W1t + idx) = o.u;
}

// W2t bf16 [768 d][4864 k]: k<4096 -> 0.25*w_out[k][d] ; k>=4096 -> W_org[d][k-4096]
__global__ __launch_bounds__(256) void k_prep_w2t(const float* __restrict__ w_out,
                                                  const float* __restrict__ W_org,
                                                  bf16* __restrict__ W2t) {
  int idx = (blockIdx.x * 256 + threadIdx.x) * 4;
  if (idx >= D_DIM * K_CAT) return;
  int d = idx / K_CAT, k0 = idx % K_CAT;
  union { uint2 u; bf16 h[4]; } o;
  if (k0 < NR) {
#pragma unroll
    for (int i = 0; i < 4; ++i) o.h[i] = (bf16)(0.25f * w_out[(k0 + i) * D_DIM + d]);
  } else {
    float4 v = *(const float4*)(W_org + d * D_DIM + (k0 - NR));
    o.h[0] = (bf16)v.x; o.h[1] = (bf16)v.y; o.h[2] = (bf16)v.z; o.h[3] = (bf16)v.w;
  }
  *(uint2*)(W2t + idx) = o.u;
}

// bias_total[d] = b_org[d] + 0.25 * sum_n b_out[n][d]  (deterministic 2-stage)
__global__ __launch_bounds__(256) void k_bias_partial(const float* __restrict__ b_out,
                                                      float* __restrict__ partial) {
  int b = blockIdx.x;
  for (int d = threadIdx.x; d < D_DIM; d += 256) {
    float s = 0.0f;
    for (int n = b * 32; n < b * 32 + 32; ++n) s += b_out[n * D_DIM + d];
    partial[b * D_DIM + d] = s;
  }
}

__global__ __launch_bounds__(256) void k_bias_final(const float* __restrict__ partial,
                                                    const float* __restrict__ b_org,
                                                    float* __restrict__ bias_total) {
  int d = blockIdx.x * 256 + threadIdx.x;
  if (d >= D_DIM) return;
  float s = 0.0f;
#pragma unroll
  for (int b = 0; b < 32; ++b) s += partial[b * D_DIM + d];
  bias_total[d] = b_org[d] + 0.25f * s;
}

// ---------------- GEMM machinery ----------------

// Stage ROWS x 32 bf16 tile (K-contiguous rows of 64B) into LDS via
// global_load_lds width 16. Chunk = 16 rows = 1024B, one wave-inst each.
// Bank-conflict fix (rule 21: both-sides-or-neither with global_load_lds):
// 16B slot s of row r holds logical slot s ^ ((r>>1)&3). The source address
// is pre-swizzled here; ds_read applies the same XOR. Spreads the previous
// 8-way same-bank-group collision across all 32 banks.
template <int ROWS>
__device__ __forceinline__ void stage_tile(const bf16* g, int ld, int row0, int col0,
                                           bf16* lds) {
  const int lane = threadIdx.x & 63;
  const int wave = threadIdx.x >> 6;
  constexpr int PW = ROWS / 64;  // chunks per wave
  const int src_slot = (lane & 3) ^ ((lane >> 3) & 3);  // (slot) ^ ((row_in>>1)&3)
#pragma unroll
  for (int c = 0; c < PW; ++c) {
    const int chunk = wave * PW + c;
    const int row = row0 + chunk * 16 + (lane >> 2);
    const bf16* gp = g + (size_t)row * ld + col0 + (src_slot << 3);
    __builtin_amdgcn_global_load_lds((gu32*)gp, (su32*)(lds + chunk * 512), 16, 0, 0);
  }
}

// swizzled 16B-slot index for ds_read of logical slot kg at tile-row lr
__device__ __forceinline__ int swz_slot(int kg, int lr) {
  return (kg ^ ((lr >> 1) & 3)) << 3;  // in bf16 elements
}

// GEMM1: Xb[4992,768] x W1t[4096,768]^T-layout -> H2 bf16 [4992,4096]
__global__ __launch_bounds__(256) void k_gemm1(const bf16* __restrict__ Xb,
                                               const bf16* __restrict__ W1t,
                                               bf16* __restrict__ H2,
                                               const float* __restrict__ b1,
                                               const float* __restrict__ midw,
                                               const float* __restrict__ midb) {
  __shared__ bf16 As[128 * 32];
  __shared__ bf16 Bs[128 * 32];
  const int wgid = xcd_swizzle(blockIdx.x, 39 * 32);
  const int bmt = wgid >> 5;             // 39 M-tiles
  const int bnt = wgid & 31;             // 32 N-tiles (consecutive share A-panel)
  const int m0 = bmt * 128, n0 = bnt * 128;
  const int lane = threadIdx.x & 63;
  const int wave = threadIdx.x >> 6;
  const int wm = wave >> 1, wn = wave & 1;
  const int lr = lane & 15, kg = lane >> 4;
  const int slot = swz_slot(kg, lr);

  f32x4 acc[4][4];
#pragma unroll
  for (int i = 0; i < 4; ++i)
#pragma unroll
    for (int j = 0; j < 4; ++j) acc[i][j] = (f32x4)(0.0f);

  for (int kt = 0; kt < 24; ++kt) {
    const int k0 = kt * 32;
    stage_tile<128>(Xb, D_DIM, m0, k0, As);
    stage_tile<128>(W1t, D_DIM, n0, k0, Bs);
    __syncthreads();
    bf16x8 a[4], b[4];
#pragma unroll
    for (int i = 0; i < 4; ++i)
      a[i] = *(const bf16x8*)(As + (wm * 64 + i * 16 + lr) * 32 + slot);
#pragma unroll
    for (int j = 0; j < 4; ++j)
      b[j] = *(const bf16x8*)(Bs + (wn * 64 + j * 16 + lr) * 32 + slot);
#pragma unroll
    for (int i = 0; i < 4; ++i)
#pragma unroll
      for (int j = 0; j < 4; ++j)
        acc[i][j] = __builtin_amdgcn_mfma_f32_16x16x32_bf16(a[i], b[j], acc[i][j], 0, 0, 0);
    __syncthreads();
  }

#pragma unroll
  for (int j = 0; j < 4; ++j) {
    const int col = n0 + wn * 64 + j * 16 + lr;
    const float b1v = b1[col];
    const float mdv = midw[(col >> 2) * 16 + (col & 3) * 5];  // mid_w[n][r][r]
    const float mbv = midb[col];
#pragma unroll
    for (int i = 0; i < 4; ++i) {
      const int r0 = m0 + wm * 64 + i * 16 + kg * 4;
#pragma unroll
      for (int rr = 0; rr < 4; ++rr) {
        float h = acc[i][j][rr] + b1v;
        h = gelu_fast(h);
        h = h * mdv + mbv;
        h = gelu_fast(h);
        H2[(size_t)(r0 + rr) * NR + col] = (bf16)h;
      }
    }
  }
}

// GEMM2: A = [H2 | Xb] (K = 4864) x W2t[768,4864] -> out/partial
// SPLITS>1: writes fp32 partial (no bias); SPLITS==1: writes out + bias.
template <int SPLITS>
__global__ __launch_bounds__(256) void k_gemm2(const bf16* __restrict__ H2,
                                               const bf16* __restrict__ Xb,
                                               const bf16* __restrict__ W2t,
                                               float* __restrict__ outp,
                                               const float* __restrict__ bias) {
  __shared__ bf16 As[128 * 32];
  __shared__ bf16 Bs[64 * 32];
  const int nwg = 39 * 12 * SPLITS;
  const int wgid = xcd_swizzle(blockIdx.x, nwg);
  const int bmt = wgid / (12 * SPLITS);
  const int rem = wgid % (12 * SPLITS);
  const int ks  = rem / 12;
  const int bnt = rem % 12;              // 12 consecutive share A-panel
  const int m0 = bmt * 128, n0 = bnt * 64;
  const int lane = threadIdx.x & 63;
  const int wave = threadIdx.x >> 6;
  const int wm = wave >> 1, wn = wave & 1;
  const int lr = lane & 15, kg = lane >> 4;
  const int slot = swz_slot(kg, lr);
  constexpr int KT_PER = KT_ALL / SPLITS;

  f32x4 acc[4][2];
#pragma unroll
  for (int i = 0; i < 4; ++i)
#pragma unroll
    for (int j = 0; j < 2; ++j) acc[i][j] = (f32x4)(0.0f);

  for (int kt = ks * KT_PER; kt < (ks + 1) * KT_PER; ++kt) {
    const int k0 = kt * 32;
    if (k0 < NR) stage_tile<128>(H2, NR, m0, k0, As);
    else         stage_tile<128>(Xb, D_DIM, m0, k0 - NR, As);
    stage_tile<64>(W2t, K_CAT, n0, k0, Bs);
    __syncthreads();
    bf16x8 a[4], b[2];
#pragma unroll
    for (int i = 0; i < 4; ++i)
      a[i] = *(const bf16x8*)(As + (wm * 64 + i * 16 + lr) * 32 + slot);
#pragma unroll
    for (int j = 0; j < 2; ++j)
      b[j] = *(const bf16x8*)(Bs + (wn * 32 + j * 16 + lr) * 32 + slot);
#pragma unroll
    for (int i = 0; i < 4; ++i)
#pragma unroll
      for (int j = 0; j < 2; ++j)
        acc[i][j] = __builtin_amdgcn_mfma_f32_16x16x32_bf16(a[i], b[j], acc[i][j], 0, 0, 0);
    __syncthreads();
  }

  float* dst = (SPLITS > 1) ? outp + (size_t)ks * M_TOK * D_DIM : outp;
#pragma unroll
  for (int j = 0; j < 2; ++j) {
    const int col = n0 + wn * 32 + j * 16 + lr;
    const float bv = (SPLITS > 1) ? 0.0f : bias[col];
#pragma unroll
    for (int i = 0; i < 4; ++i) {
      const int r0 = m0 + wm * 64 + i * 16 + kg * 4;
#pragma unroll
      for (int rr = 0; rr < 4; ++rr) {
        const int row = r0 + rr;
        if (row < M_TOK) dst[(size_t)row * D_DIM + col] = acc[i][j][rr] + bv;
      }
    }
  }
}

// out = sum_s partial[s] + bias  (vectorized float4)
template <int SPLITS>
__global__ __launch_bounds__(256) void k_reduce(const float* __restrict__ padd,
                                                const float* __restrict__ bias,
                                                float* __restrict__ out) {
  int idx = (blockIdx.x * 256 + threadIdx.x) * 4;
  if (idx >= M_TOK * D_DIM) return;
  float4 s = *(const float4*)(bias + (idx % D_DIM));
#pragma unroll
  for (int p = 0; p < SPLITS; ++p) {
    float4 v = *(const float4*)(padd + (size_t)p * M_TOK * D_DIM + idx);
    s.x += v.x; s.y += v.y; s.z += v.z; s.w += v.w;
  }
  *(float4*)(out + idx) = s;
}

// ---------------- launch ----------------

extern "C" void kernel_launch(void* const* d_in, const int* in_sizes, int n_in,
                              void* d_out, int out_size, void* d_ws, size_t ws_size,
                              hipStream_t stream) {
  const float* x     = (const float*)d_in[0];
  const float* W_org = (const float*)d_in[1];
  const float* b_org = (const float*)d_in[2];
  const float* w1    = (const float*)d_in[3];
  const float* b1    = (const float*)d_in[4];
  const float* mid_w = (const float*)d_in[5];
  const float* mid_b = (const float*)d_in[6];
  const float* w_out = (const float*)d_in[7];
  const float* b_out = (const float*)d_in[8];
  float* out = (float*)d_out;

  // workspace carve-up
  bf16* Xb   = (bf16*)d_ws;                         // 4992*768
  bf16* W1t  = Xb  + (size_t)M_PAD * D_DIM;         // 4096*768
  bf16* W2t  = W1t + (size_t)NR * D_DIM;            // 768*4864
  bf16* H2   = W2t + (size_t)D_DIM * K_CAT;         // 4992*4096
  float* bias    = (float*)(H2 + (size_t)M_PAD * NR);
  float* partial = bias + 1024;                     // 32*768 floats
  float* padd    = partial + 32 * D_DIM;            // SPLITS * 4928*768 floats

  const size_t base_bytes = (size_t)((char*)padd - (char*)d_ws);
  const size_t per_split  = (size_t)M_TOK * D_DIM * sizeof(float);
  int S = 1;
  if (ws_size >= base_bytes + 4 * per_split)      S = 4;
  else if (ws_size >= base_bytes + 2 * per_split) S = 2;

  k_prep_x   <<<(M_PAD * D_DIM / 4) / 256, 256, 0, stream>>>(x, Xb);
  k_prep_w1t <<<(NR * D_DIM / 4) / 256, 256, 0, stream>>>(w1, W1t);
  k_prep_w2t <<<(D_DIM * K_CAT / 4) / 256, 256, 0, stream>>>(w_out, W_org, W2t);
  k_bias_partial<<<32, 256, 0, stream>>>(b_out, partial);
  k_bias_final  <<<3, 256, 0, stream>>>(partial, b_org, bias);

  k_gemm1<<<39 * 32, 256, 0, stream>>>(Xb, W1t, H2, b1, mid_w, mid_b);

  const int red_grid = (M_TOK * D_DIM / 4 + 255) / 256;
  if (S == 4) {
    k_gemm2<4><<<39 * 12 * 4, 256, 0, stream>>>(H2, Xb, W2t, padd, bias);
    k_reduce<4><<<red_grid, 256, 0, stream>>>(padd, bias, out);
  } else if (S == 2) {
    k_gemm2<2><<<39 * 12 * 2, 256, 0, stream>>>(H2, Xb, W2t, padd, bias);
    k_reduce<2><<<red_grid, 256, 0, stream>>>(padd, bias, out);
  } else {
    k_gemm2<1><<<39 * 12, 256, 0, stream>>>(H2, Xb, W2t, out, bias);
  }
}

// Round 5
// 163.153 us; speedup vs baseline: 1.2409x; 1.0692x over previous
//
#include <hip/hip_runtime.h>
#include <hip/hip_bf16.h>

// Problem constants
#define M_TOK 4928   // B*T = 64*77
#define M_PAD 4992   // 39 * 128
#define D_DIM 768
#define NR    4096   // N*R = 1024*4
#define K_CAT 4864   // NR + D_DIM (concat-K for gemm2)
#define KT_ALL 152   // K_CAT / 32

typedef __bf16 bf16;
typedef __attribute__((ext_vector_type(8))) __bf16 bf16x8;
typedef __attribute__((ext_vector_type(4))) float f32x4;
typedef __attribute__((address_space(1))) uint32_t gu32;
typedef __attribute__((address_space(3))) uint32_t su32;

// tanh-form gelu via sigmoid: x * sigmoid(1.5957692*(x + 0.044715 x^3)).
// Max abs err vs exact ~3e-4; output error budget dominated by bf16 org-path
// rounding (1.6e-2 vs 5.8e-2 threshold). ~8 VALU insts vs ~30+ for erff.
__device__ __forceinline__ float gelu_fast(float v) {
  float p = v * v;
  float u = v * fmaf(0.07135481283f, p, 1.595769122f);
  float e = __expf(-u);
  return v * __builtin_amdgcn_rcpf(1.0f + e);
}

// m204 bijective XCD swizzle: consecutive logical wgids land on one XCD.
__device__ __forceinline__ int xcd_swizzle(int orig, int nwg) {
  const int q = nwg >> 3, r = nwg & 7;
  const int x = orig & 7, rest = orig >> 3;
  return (x < r ? x * (q + 1) : r * (q + 1) + (x - r) * q) + rest;
}

// ---------------- prep kernels ----------------

__global__ __launch_bounds__(256) void k_prep_x(const float* __restrict__ x,
                                                bf16* __restrict__ Xb) {
  int idx = (blockIdx.x * 256 + threadIdx.x) * 4;
  if (idx >= M_PAD * D_DIM) return;
  int m = idx / D_DIM;
  union { uint2 u; bf16 h[4]; } o;
  if (m < M_TOK) {
    float4 v = *(const float4*)(x + idx);
    o.h[0] = (bf16)v.x; o.h[1] = (bf16)v.y; o.h[2] = (bf16)v.z; o.h[3] = (bf16)v.w;
  } else {
    o.h[0] = o.h[1] = o.h[2] = o.h[3] = (bf16)0.0f;
  }
  *(uint2*)(Xb + idx) = o.u;
}

// w1 fp32 [N=1024][D=768][R=4] -> W1t bf16 [4096 j][768 d] (K-major), j = n*4+r
__global__ __launch_bounds__(256) void k_prep_w1t(const float* __restrict__ w1,
                                                  bf16* __restrict__ W1t) {
  int idx = (blockIdx.x * 256 + threadIdx.x) * 4;
  if (idx >= NR * D_DIM) return;
  int j = idx / D_DIM, d0 = idx % D_DIM;
  int n = j >> 2, r = j & 3;
  const float* src = w1 + n * (D_DIM * 4) + r;
  union { uint2 u; bf16 h[4]; } o;
#pragma unroll
  for (int i = 0; i < 4; ++i) o.h[i] = (bf16)src[(d0 + i) * 4];
  *(uint2*)(W1t + idx) = o.u;
}

// w_out fp32 [4096 k][768 d] -> W2t[d][k] (x0.25) via LDS 64x64 transpose.
// Coalesced read (row-major k), conflict-free LDS (pitch 65), coalesced write.
__global__ __launch_bounds__(256) void k_prep_w2t_t(const float* __restrict__ w_out,
                                                    bf16* __restrict__ W2t) {
  __shared__ float S[64 * 65];
  const int bk = blockIdx.x & 63, bd = blockIdx.x >> 6;  // 64 k-tiles x 12 d-tiles
  const int k0 = bk * 64, d0 = bd * 64;
  const int tr = threadIdx.x >> 4;        // 0..15
  const int tc = (threadIdx.x & 15) * 4;  // 0..60
#pragma unroll
  for (int p = 0; p < 4; ++p) {
    const int kr = tr + p * 16;
    float4 v = *(const float4*)(w_out + (size_t)(k0 + kr) * D_DIM + d0 + tc);
    S[kr * 65 + tc + 0] = v.x; S[kr * 65 + tc + 1] = v.y;
    S[kr * 65 + tc + 2] = v.z; S[kr * 65 + tc + 3] = v.w;
  }
  __syncthreads();
#pragma unroll
  for (int p = 0; p < 4; ++p) {
    const int dr = tr + p * 16;
    union { uint2 u; bf16 h[4]; } o;
#pragma unroll
    for (int i = 0; i < 4; ++i) o.h[i] = (bf16)(0.25f * S[(tc + i) * 65 + dr]);
    *(uint2*)(W2t + (size_t)(d0 + dr) * K_CAT + k0 + tc) = o.u;
  }
}

// W_org fp32 [768 d][768 k] -> W2t[d][4096 + k]  (already row-major: plain copy)
__global__ __launch_bounds__(256) void k_prep_w2t_org(const float* __restrict__ W_org,
                                                      bf16* __restrict__ W2t) {
  int idx = (blockIdx.x * 256 + threadIdx.x) * 4;
  if (idx >= D_DIM * D_DIM) return;
  int d = idx / D_DIM, c = idx % D_DIM;
  float4 v = *(const float4*)(W_org + idx);
  union { uint2 u; bf16 h[4]; } o;
  o.h[0] = (bf16)v.x; o.h[1] = (bf16)v.y; o.h[2] = (bf16)v.z; o.h[3] = (bf16)v.w;
  *(uint2*)(W2t + (size_t)d * K_CAT + NR + c) = o.u;
}

// bias_total[d] = b_org[d] + 0.25 * sum_n b_out[n][d]  (deterministic 2-stage)
__global__ __launch_bounds__(256) void k_bias_partial(const float* __restrict__ b_out,
                                                      float* __restrict__ partial) {
  int b = blockIdx.x;
  for (int d = threadIdx.x; d < D_DIM; d += 256) {
    float s = 0.0f;
    for (int n = b * 32; n < b * 32 + 32; ++n) s += b_out[n * D_DIM + d];
    partial[b * D_DIM + d] = s;
  }
}

__global__ __launch_bounds__(256) void k_bias_final(const float* __restrict__ partial,
                                                    const float* __restrict__ b_org,
                                                    float* __restrict__ bias_total) {
  int d = blockIdx.x * 256 + threadIdx.x;
  if (d >= D_DIM) return;
  float s = 0.0f;
#pragma unroll
  for (int b = 0; b < 32; ++b) s += partial[b * D_DIM + d];
  bias_total[d] = b_org[d] + 0.25f * s;
}

// ---------------- GEMM machinery ----------------

// Stage ROWS x 32 bf16 tile into LDS via global_load_lds width 16.
// Bank-conflict swizzle (rule 21, verified R4: conflicts -> 0): slot s of row
// r holds logical slot s ^ ((r>>1)&3); source pre-swizzled, ds_read XORs back.
template <int ROWS>
__device__ __forceinline__ void stage_tile(const bf16* g, int ld, int row0, int col0,
                                           bf16* lds) {
  const int lane = threadIdx.x & 63;
  const int wave = threadIdx.x >> 6;
  constexpr int PW = ROWS / 64;  // chunks per wave
  const int src_slot = (lane & 3) ^ ((lane >> 3) & 3);
#pragma unroll
  for (int c = 0; c < PW; ++c) {
    const int chunk = wave * PW + c;
    const int row = row0 + chunk * 16 + (lane >> 2);
    const bf16* gp = g + (size_t)row * ld + col0 + (src_slot << 3);
    __builtin_amdgcn_global_load_lds((gu32*)gp, (su32*)(lds + chunk * 512), 16, 0, 0);
  }
}

__device__ __forceinline__ int swz_slot(int kg, int lr) {
  return (kg ^ ((lr >> 1) & 3)) << 3;  // bf16 elements
}

// GEMM1: Xb[4992,768] x W1t[4096,768] -> H2 bf16 [4992,4096]
// Double-buffered: stage(t+1) issued BEFORE ds_read+MFMA(t); one barrier/iter.
__global__ __launch_bounds__(256) void k_gemm1(const bf16* __restrict__ Xb,
                                               const bf16* __restrict__ W1t,
                                               bf16* __restrict__ H2,
                                               const float* __restrict__ b1,
                                               const float* __restrict__ midw,
                                               const float* __restrict__ midb) {
  __shared__ bf16 As[2][128 * 32];
  __shared__ bf16 Bs[2][128 * 32];
  const int wgid = xcd_swizzle(blockIdx.x, 39 * 32);
  const int bmt = wgid >> 5;
  const int bnt = wgid & 31;
  const int m0 = bmt * 128, n0 = bnt * 128;
  const int lane = threadIdx.x & 63;
  const int wave = threadIdx.x >> 6;
  const int wm = wave >> 1, wn = wave & 1;
  const int lr = lane & 15, kg = lane >> 4;
  const int slot = swz_slot(kg, lr);

  f32x4 acc[4][4];
#pragma unroll
  for (int i = 0; i < 4; ++i)
#pragma unroll
    for (int j = 0; j < 4; ++j) acc[i][j] = (f32x4)(0.0f);

  stage_tile<128>(Xb, D_DIM, m0, 0, As[0]);
  stage_tile<128>(W1t, D_DIM, n0, 0, Bs[0]);
  __syncthreads();

  int cur = 0;
  for (int kt = 0; kt < 24; ++kt) {
    if (kt + 1 < 24) {
      stage_tile<128>(Xb, D_DIM, m0, (kt + 1) * 32, As[cur ^ 1]);
      stage_tile<128>(W1t, D_DIM, n0, (kt + 1) * 32, Bs[cur ^ 1]);
    }
    bf16x8 a[4], b[4];
#pragma unroll
    for (int i = 0; i < 4; ++i)
      a[i] = *(const bf16x8*)(As[cur] + (wm * 64 + i * 16 + lr) * 32 + slot);
#pragma unroll
    for (int j = 0; j < 4; ++j)
      b[j] = *(const bf16x8*)(Bs[cur] + (wn * 64 + j * 16 + lr) * 32 + slot);
#pragma unroll
    for (int i = 0; i < 4; ++i)
#pragma unroll
      for (int j = 0; j < 4; ++j)
        acc[i][j] = __builtin_amdgcn_mfma_f32_16x16x32_bf16(a[i], b[j], acc[i][j], 0, 0, 0);
    __syncthreads();  // drains next-tile loads (vmcnt) + this tile's ds_reads
    cur ^= 1;
  }

#pragma unroll
  for (int j = 0; j < 4; ++j) {
    const int col = n0 + wn * 64 + j * 16 + lr;
    const float b1v = b1[col];
    const float mdv = midw[(col >> 2) * 16 + (col & 3) * 5];  // mid_w[n][r][r]
    const float mbv = midb[col];
#pragma unroll
    for (int i = 0; i < 4; ++i) {
      const int r0 = m0 + wm * 64 + i * 16 + kg * 4;
#pragma unroll
      for (int rr = 0; rr < 4; ++rr) {
        float h = acc[i][j][rr] + b1v;
        h = gelu_fast(h);
        h = h * mdv + mbv;
        h = gelu_fast(h);
        H2[(size_t)(r0 + rr) * NR + col] = (bf16)h;
      }
    }
  }
}

// GEMM2: A = [H2 | Xb] (K=4864) x W2t[768,4864] -> out/partial.  BN=128,
// double-buffered, split-K.  SPLITS>1: fp32 partial; SPLITS==1: out + bias.
template <int SPLITS>
__global__ __launch_bounds__(256) void k_gemm2(const bf16* __restrict__ H2,
                                               const bf16* __restrict__ Xb,
                                               const bf16* __restrict__ W2t,
                                               float* __restrict__ outp,
                                               const float* __restrict__ bias) {
  __shared__ bf16 As[2][128 * 32];
  __shared__ bf16 Bs[2][128 * 32];
  const int nwg = 39 * 6 * SPLITS;
  const int wgid = xcd_swizzle(blockIdx.x, nwg);
  const int bmt = wgid / (6 * SPLITS);
  const int rem = wgid % (6 * SPLITS);
  const int ks  = rem / 6;
  const int bnt = rem % 6;               // 6 consecutive share A-panel
  const int m0 = bmt * 128, n0 = bnt * 128;
  const int lane = threadIdx.x & 63;
  const int wave = threadIdx.x >> 6;
  const int wm = wave >> 1, wn = wave & 1;
  const int lr = lane & 15, kg = lane >> 4;
  const int slot = swz_slot(kg, lr);
  constexpr int KT_PER = KT_ALL / SPLITS;
  const int kt0 = ks * KT_PER, kt1 = kt0 + KT_PER;

  auto stageA = [&](int kt, bf16* dst) {
    const int k0 = kt * 32;
    if (k0 < NR) stage_tile<128>(H2, NR, m0, k0, dst);
    else         stage_tile<128>(Xb, D_DIM, m0, k0 - NR, dst);
  };

  f32x4 acc[4][4];
#pragma unroll
  for (int i = 0; i < 4; ++i)
#pragma unroll
    for (int j = 0; j < 4; ++j) acc[i][j] = (f32x4)(0.0f);

  stageA(kt0, As[0]);
  stage_tile<128>(W2t, K_CAT, n0, kt0 * 32, Bs[0]);
  __syncthreads();

  int cur = 0;
  for (int kt = kt0; kt < kt1; ++kt) {
    if (kt + 1 < kt1) {
      stageA(kt + 1, As[cur ^ 1]);
      stage_tile<128>(W2t, K_CAT, n0, (kt + 1) * 32, Bs[cur ^ 1]);
    }
    bf16x8 a[4], b[4];
#pragma unroll
    for (int i = 0; i < 4; ++i)
      a[i] = *(const bf16x8*)(As[cur] + (wm * 64 + i * 16 + lr) * 32 + slot);
#pragma unroll
    for (int j = 0; j < 4; ++j)
      b[j] = *(const bf16x8*)(Bs[cur] + (wn * 64 + j * 16 + lr) * 32 + slot);
#pragma unroll
    for (int i = 0; i < 4; ++i)
#pragma unroll
      for (int j = 0; j < 4; ++j)
        acc[i][j] = __builtin_amdgcn_mfma_f32_16x16x32_bf16(a[i], b[j], acc[i][j], 0, 0, 0);
    __syncthreads();
    cur ^= 1;
  }

  float* dst = (SPLITS > 1) ? outp + (size_t)ks * M_TOK * D_DIM : outp;
#pragma unroll
  for (int j = 0; j < 4; ++j) {
    const int col = n0 + wn * 64 + j * 16 + lr;
    const float bv = (SPLITS > 1) ? 0.0f : bias[col];
#pragma unroll
    for (int i = 0; i < 4; ++i) {
      const int r0 = m0 + wm * 64 + i * 16 + kg * 4;
#pragma unroll
      for (int rr = 0; rr < 4; ++rr) {
        const int row = r0 + rr;
        if (row < M_TOK) dst[(size_t)row * D_DIM + col] = acc[i][j][rr] + bv;
      }
    }
  }
}

// out = sum_s partial[s] + bias  (vectorized float4)
template <int SPLITS>
__global__ __launch_bounds__(256) void k_reduce(const float* __restrict__ padd,
                                                const float* __restrict__ bias,
                                                float* __restrict__ out) {
  int idx = (blockIdx.x * 256 + threadIdx.x) * 4;
  if (idx >= M_TOK * D_DIM) return;
  float4 s = *(const float4*)(bias + (idx % D_DIM));
#pragma unroll
  for (int p = 0; p < SPLITS; ++p) {
    float4 v = *(const float4*)(padd + (size_t)p * M_TOK * D_DIM + idx);
    s.x += v.x; s.y += v.y; s.z += v.z; s.w += v.w;
  }
  *(float4*)(out + idx) = s;
}

// ---------------- launch ----------------

extern "C" void kernel_launch(void* const* d_in, const int* in_sizes, int n_in,
                              void* d_out, int out_size, void* d_ws, size_t ws_size,
                              hipStream_t stream) {
  const float* x     = (const float*)d_in[0];
  const float* W_org = (const float*)d_in[1];
  const float* b_org = (const float*)d_in[2];
  const float* w1    = (const float*)d_in[3];
  const float* b1    = (const float*)d_in[4];
  const float* mid_w = (const float*)d_in[5];
  const float* mid_b = (const float*)d_in[6];
  const float* w_out = (const float*)d_in[7];
  const float* b_out = (const float*)d_in[8];
  float* out = (float*)d_out;

  // workspace carve-up
  bf16* Xb   = (bf16*)d_ws;                         // 4992*768
  bf16* W1t  = Xb  + (size_t)M_PAD * D_DIM;         // 4096*768
  bf16* W2t  = W1t + (size_t)NR * D_DIM;            // 768*4864
  bf16* H2   = W2t + (size_t)D_DIM * K_CAT;         // 4992*4096
  float* bias    = (float*)(H2 + (size_t)M_PAD * NR);
  float* partial = bias + 1024;                     // 32*768 floats
  float* padd    = partial + 32 * D_DIM;            // SPLITS * 4928*768 floats

  const size_t base_bytes = (size_t)((char*)padd - (char*)d_ws);
  const size_t per_split  = (size_t)M_TOK * D_DIM * sizeof(float);
  int S = 1;
  if (ws_size >= base_bytes + 4 * per_split)      S = 4;
  else if (ws_size >= base_bytes + 2 * per_split) S = 2;

  k_prep_x     <<<(M_PAD * D_DIM / 4) / 256, 256, 0, stream>>>(x, Xb);
  k_prep_w1t   <<<(NR * D_DIM / 4) / 256, 256, 0, stream>>>(w1, W1t);
  k_prep_w2t_t <<<64 * 12, 256, 0, stream>>>(w_out, W2t);
  k_prep_w2t_org<<<(D_DIM * D_DIM / 4 + 255) / 256, 256, 0, stream>>>(W_org, W2t);
  k_bias_partial<<<32, 256, 0, stream>>>(b_out, partial);
  k_bias_final  <<<3, 256, 0, stream>>>(partial, b_org, bias);

  k_gemm1<<<39 * 32, 256, 0, stream>>>(Xb, W1t, H2, b1, mid_w, mid_b);

  const int red_grid = (M_TOK * D_DIM / 4 + 255) / 256;
  if (S == 4) {
    k_gemm2<4><<<39 * 6 * 4, 256, 0, stream>>>(H2, Xb, W2t, padd, bias);
    k_reduce<4><<<red_grid, 256, 0, stream>>>(padd, bias, out);
  } else if (S == 2) {
    k_gemm2<2><<<39 * 6 * 2, 256, 0, stream>>>(H2, Xb, W2t, padd, bias);
    k_reduce<2><<<red_grid, 256, 0, stream>>>(padd, bias, out);
  } else {
    k_gemm2<1><<<39 * 6, 256, 0, stream>>>(H2, Xb, W2t, out, bias);
  }
}

// Round 6
// 156.150 us; speedup vs baseline: 1.2966x; 1.0448x over previous
//
#include <hip/hip_runtime.h>
#include <hip/hip_bf16.h>

// Problem constants
#define M_TOK 4928   // B*T = 64*77
#define M_PAD 4992   // 39 * 128
#define D_DIM 768
#define NR    4096   // N*R = 1024*4
#define K_CAT 4864   // NR + D_DIM (concat-K for gemm2)
#define KT_ALL 152   // K_CAT / 32

typedef __bf16 bf16;
typedef __attribute__((ext_vector_type(8))) __bf16 bf16x8;
typedef __attribute__((ext_vector_type(4))) float f32x4;
typedef __attribute__((address_space(1))) uint32_t gu32;
typedef __attribute__((address_space(3))) uint32_t su32;

// tanh-form gelu via sigmoid; max abs err ~3e-4 (budget: 1.6e-2 vs 5.8e-2 thr)
__device__ __forceinline__ float gelu_fast(float v) {
  float p = v * v;
  float u = v * fmaf(0.07135481283f, p, 1.595769122f);
  float e = __expf(-u);
  return v * __builtin_amdgcn_rcpf(1.0f + e);
}

// m204 bijective XCD swizzle: consecutive logical wgids land on one XCD.
__device__ __forceinline__ int xcd_swizzle(int orig, int nwg) {
  const int q = nwg >> 3, r = nwg & 7;
  const int x = orig & 7, rest = orig >> 3;
  return (x < r ? x * (q + 1) : r * (q + 1) + (x - r) * q) + rest;
}

// ---------------- prep kernels ----------------

__global__ __launch_bounds__(256) void k_prep_x(const float* __restrict__ x,
                                                bf16* __restrict__ Xb) {
  int idx = (blockIdx.x * 256 + threadIdx.x) * 4;
  if (idx >= M_PAD * D_DIM) return;
  int m = idx / D_DIM;
  union { uint2 u; bf16 h[4]; } o;
  if (m < M_TOK) {
    float4 v = *(const float4*)(x + idx);
    o.h[0] = (bf16)v.x; o.h[1] = (bf16)v.y; o.h[2] = (bf16)v.z; o.h[3] = (bf16)v.w;
  } else {
    o.h[0] = o.h[1] = o.h[2] = o.h[3] = (bf16)0.0f;
  }
  *(uint2*)(Xb + idx) = o.u;
}

// w1 fp32 [N=1024][D=768][R=4] -> W1t bf16 [4096 j][768 d] (K-major), j = n*4+r
__global__ __launch_bounds__(256) void k_prep_w1t(const float* __restrict__ w1,
                                                  bf16* __restrict__ W1t) {
  int idx = (blockIdx.x * 256 + threadIdx.x) * 4;
  if (idx >= NR * D_DIM) return;
  int j = idx / D_DIM, d0 = idx % D_DIM;
  int n = j >> 2, r = j & 3;
  const float* src = w1 + n * (D_DIM * 4) + r;
  union { uint2 u; bf16 h[4]; } o;
#pragma unroll
  for (int i = 0; i < 4; ++i) o.h[i] = (bf16)src[(d0 + i) * 4];
  *(uint2*)(W1t + idx) = o.u;
}

// w_out fp32 [4096 k][768 d] -> W2t[d][k] (x0.25) via LDS 64x64 transpose.
__global__ __launch_bounds__(256) void k_prep_w2t_t(const float* __restrict__ w_out,
                                                    bf16* __restrict__ W2t) {
  __shared__ float S[64 * 65];
  const int bk = blockIdx.x & 63, bd = blockIdx.x >> 6;  // 64 k-tiles x 12 d-tiles
  const int k0 = bk * 64, d0 = bd * 64;
  const int tr = threadIdx.x >> 4;        // 0..15
  const int tc = (threadIdx.x & 15) * 4;  // 0..60
#pragma unroll
  for (int p = 0; p < 4; ++p) {
    const int kr = tr + p * 16;
    float4 v = *(const float4*)(w_out + (size_t)(k0 + kr) * D_DIM + d0 + tc);
    S[kr * 65 + tc + 0] = v.x; S[kr * 65 + tc + 1] = v.y;
    S[kr * 65 + tc + 2] = v.z; S[kr * 65 + tc + 3] = v.w;
  }
  __syncthreads();
#pragma unroll
  for (int p = 0; p < 4; ++p) {
    const int dr = tr + p * 16;
    union { uint2 u; bf16 h[4]; } o;
#pragma unroll
    for (int i = 0; i < 4; ++i) o.h[i] = (bf16)(0.25f * S[(tc + i) * 65 + dr]);
    *(uint2*)(W2t + (size_t)(d0 + dr) * K_CAT + k0 + tc) = o.u;
  }
}

// W_org fp32 [768 d][768 k] -> W2t[d][4096 + k]  (row-major: plain copy)
__global__ __launch_bounds__(256) void k_prep_w2t_org(const float* __restrict__ W_org,
                                                      bf16* __restrict__ W2t) {
  int idx = (blockIdx.x * 256 + threadIdx.x) * 4;
  if (idx >= D_DIM * D_DIM) return;
  int d = idx / D_DIM, c = idx % D_DIM;
  float4 v = *(const float4*)(W_org + idx);
  union { uint2 u; bf16 h[4]; } o;
  o.h[0] = (bf16)v.x; o.h[1] = (bf16)v.y; o.h[2] = (bf16)v.z; o.h[3] = (bf16)v.w;
  *(uint2*)(W2t + (size_t)d * K_CAT + NR + c) = o.u;
}

// bias_total[d] = b_org[d] + 0.25 * sum_n b_out[n][d]  (deterministic 2-stage)
__global__ __launch_bounds__(256) void k_bias_partial(const float* __restrict__ b_out,
                                                      float* __restrict__ partial) {
  int b = blockIdx.x;
  for (int d = threadIdx.x; d < D_DIM; d += 256) {
    float s = 0.0f;
    for (int n = b * 32; n < b * 32 + 32; ++n) s += b_out[n * D_DIM + d];
    partial[b * D_DIM + d] = s;
  }
}

__global__ __launch_bounds__(256) void k_bias_final(const float* __restrict__ partial,
                                                    const float* __restrict__ b_org,
                                                    float* __restrict__ bias_total) {
  int d = blockIdx.x * 256 + threadIdx.x;
  if (d >= D_DIM) return;
  float s = 0.0f;
#pragma unroll
  for (int b = 0; b < 32; ++b) s += partial[b * D_DIM + d];
  bias_total[d] = b_org[d] + 0.25f * s;
}

// ---------------- GEMM machinery ----------------

// Stage 128 x 32 bf16 tile into LDS via global_load_lds width 16.
// 2 instructions per wave (vmcnt events). Bank-conflict swizzle verified R4
// (conflicts -> 0): slot s of row r holds slot s ^ ((r>>1)&3).
__device__ __forceinline__ void stage_tile(const bf16* g, int ld, int row0, int col0,
                                           bf16* lds) {
  const int lane = threadIdx.x & 63;
  const int wave = threadIdx.x >> 6;
  const int src_slot = (lane & 3) ^ ((lane >> 3) & 3);
#pragma unroll
  for (int c = 0; c < 2; ++c) {
    const int chunk = wave * 2 + c;
    const int row = row0 + chunk * 16 + (lane >> 2);
    const bf16* gp = g + (size_t)row * ld + col0 + (src_slot << 3);
    __builtin_amdgcn_global_load_lds((gu32*)gp, (su32*)(lds + chunk * 512), 16, 0, 0);
  }
}

__device__ __forceinline__ int swz_slot(int kg, int lr) {
  return (kg ^ ((lr >> 1) & 3)) << 3;  // bf16 elements
}

#define TILE_E (128 * 32)

// 3-buffer counted-vmcnt pipeline (T4): tiles t,t+1 in flight (8 loads/wave),
// wait vmcnt(4) per iter (NEVER 0 until the tail), one raw s_barrier per iter.
// Safety: ds_reads of buf[t] complete (lgkmcnt before MFMA) before
// barrier(t+1); stage into that buffer is issued only after barrier(t+1).
#define PIPE_LOOP(KT0, KT1, STAGE_PAIR, BODY)                                   \
  {                                                                             \
    STAGE_PAIR(KT0, 0);                                                         \
    STAGE_PAIR((KT0) + 1, 1);                                                   \
    int ra = 0;                                                                 \
    for (int kt = (KT0); kt < (KT1); ++kt) {                                    \
      if (kt + 1 < (KT1)) { asm volatile("s_waitcnt vmcnt(4)" ::: "memory"); }  \
      else                { asm volatile("s_waitcnt vmcnt(0)" ::: "memory"); }  \
      asm volatile("s_barrier" ::: "memory");                                   \
      const int rs = ra + 2 >= 3 ? ra - 1 : ra + 2;                             \
      BODY(ra);                                                                 \
      if (kt + 2 < (KT1)) STAGE_PAIR(kt + 2, rs);                               \
      ra = (ra + 1 == 3) ? 0 : ra + 1;                                          \
    }                                                                           \
  }

// GEMM1: Xb[4992,768] x W1t[4096,768] -> H2 bf16 [4992,4096]
__global__ __launch_bounds__(256) void k_gemm1(const bf16* __restrict__ Xb,
                                               const bf16* __restrict__ W1t,
                                               bf16* __restrict__ H2,
                                               const float* __restrict__ b1,
                                               const float* __restrict__ midw,
                                               const float* __restrict__ midb) {
  __shared__ bf16 As[3][TILE_E];
  __shared__ bf16 Bs[3][TILE_E];
  const int wgid = xcd_swizzle(blockIdx.x, 39 * 32);
  const int bmt = wgid >> 5;
  const int bnt = wgid & 31;
  const int m0 = bmt * 128, n0 = bnt * 128;
  const int lane = threadIdx.x & 63;
  const int wave = threadIdx.x >> 6;
  const int wm = wave >> 1, wn = wave & 1;
  const int lr = lane & 15, kg = lane >> 4;
  const int slot = swz_slot(kg, lr);

  f32x4 acc[4][4];
#pragma unroll
  for (int i = 0; i < 4; ++i)
#pragma unroll
    for (int j = 0; j < 4; ++j) acc[i][j] = (f32x4)(0.0f);

#define G1_STAGE(kt, buf)                                   \
  {                                                         \
    stage_tile(Xb, D_DIM, m0, (kt) * 32, As[(buf)]);        \
    stage_tile(W1t, D_DIM, n0, (kt) * 32, Bs[(buf)]);       \
  }
#define G1_BODY(cur)                                                         \
  {                                                                          \
    bf16x8 a[4], b[4];                                                       \
    _Pragma("unroll") for (int i = 0; i < 4; ++i)                            \
      a[i] = *(const bf16x8*)(As[(cur)] + (wm * 64 + i * 16 + lr) * 32 + slot); \
    _Pragma("unroll") for (int j = 0; j < 4; ++j)                            \
      b[j] = *(const bf16x8*)(Bs[(cur)] + (wn * 64 + j * 16 + lr) * 32 + slot); \
    _Pragma("unroll") for (int i = 0; i < 4; ++i)                            \
      _Pragma("unroll") for (int j = 0; j < 4; ++j)                          \
        acc[i][j] = __builtin_amdgcn_mfma_f32_16x16x32_bf16(a[i], b[j], acc[i][j], 0, 0, 0); \
  }

  PIPE_LOOP(0, 24, G1_STAGE, G1_BODY)

#pragma unroll
  for (int j = 0; j < 4; ++j) {
    const int col = n0 + wn * 64 + j * 16 + lr;
    const float b1v = b1[col];
    const float mdv = midw[(col >> 2) * 16 + (col & 3) * 5];  // mid_w[n][r][r]
    const float mbv = midb[col];
#pragma unroll
    for (int i = 0; i < 4; ++i) {
      const int r0 = m0 + wm * 64 + i * 16 + kg * 4;
#pragma unroll
      for (int rr = 0; rr < 4; ++rr) {
        float h = acc[i][j][rr] + b1v;
        h = gelu_fast(h);
        h = h * mdv + mbv;
        h = gelu_fast(h);
        H2[(size_t)(r0 + rr) * NR + col] = (bf16)h;
      }
    }
  }
}

// GEMM2: A = [H2 | Xb] (K=4864) x W2t[768,4864] -> out/partial. BN=128, split-K.
template <int SPLITS>
__global__ __launch_bounds__(256) void k_gemm2(const bf16* __restrict__ H2,
                                               const bf16* __restrict__ Xb,
                                               const bf16* __restrict__ W2t,
                                               float* __restrict__ outp,
                                               const float* __restrict__ bias) {
  __shared__ bf16 As[3][TILE_E];
  __shared__ bf16 Bs[3][TILE_E];
  const int nwg = 39 * 6 * SPLITS;
  const int wgid = xcd_swizzle(blockIdx.x, nwg);
  const int bmt = wgid / (6 * SPLITS);
  const int rem = wgid % (6 * SPLITS);
  const int ks  = rem / 6;
  const int bnt = rem % 6;               // 6 consecutive share A-panel
  const int m0 = bmt * 128, n0 = bnt * 128;
  const int lane = threadIdx.x & 63;
  const int wave = threadIdx.x >> 6;
  const int wm = wave >> 1, wn = wave & 1;
  const int lr = lane & 15, kg = lane >> 4;
  const int slot = swz_slot(kg, lr);
  constexpr int KT_PER = KT_ALL / SPLITS;
  const int kt0 = ks * KT_PER, kt1 = kt0 + KT_PER;

  f32x4 acc[4][4];
#pragma unroll
  for (int i = 0; i < 4; ++i)
#pragma unroll
    for (int j = 0; j < 4; ++j) acc[i][j] = (f32x4)(0.0f);

#define G2_STAGE(kt, buf)                                           \
  {                                                                 \
    const int k0s = (kt) * 32;                                      \
    if (k0s < NR) stage_tile(H2, NR, m0, k0s, As[(buf)]);           \
    else          stage_tile(Xb, D_DIM, m0, k0s - NR, As[(buf)]);   \
    stage_tile(W2t, K_CAT, n0, k0s, Bs[(buf)]);                     \
  }
#define G2_BODY(cur)                                                         \
  {                                                                          \
    bf16x8 a[4], b[4];                                                       \
    _Pragma("unroll") for (int i = 0; i < 4; ++i)                            \
      a[i] = *(const bf16x8*)(As[(cur)] + (wm * 64 + i * 16 + lr) * 32 + slot); \
    _Pragma("unroll") for (int j = 0; j < 4; ++j)                            \
      b[j] = *(const bf16x8*)(Bs[(cur)] + (wn * 64 + j * 16 + lr) * 32 + slot); \
    _Pragma("unroll") for (int i = 0; i < 4; ++i)                            \
      _Pragma("unroll") for (int j = 0; j < 4; ++j)                          \
        acc[i][j] = __builtin_amdgcn_mfma_f32_16x16x32_bf16(a[i], b[j], acc[i][j], 0, 0, 0); \
  }

  PIPE_LOOP(kt0, kt1, G2_STAGE, G2_BODY)

  float* dst = (SPLITS > 1) ? outp + (size_t)ks * M_TOK * D_DIM : outp;
#pragma unroll
  for (int j = 0; j < 4; ++j) {
    const int col = n0 + wn * 64 + j * 16 + lr;
    const float bv = (SPLITS > 1) ? 0.0f : bias[col];
#pragma unroll
    for (int i = 0; i < 4; ++i) {
      const int r0 = m0 + wm * 64 + i * 16 + kg * 4;
#pragma unroll
      for (int rr = 0; rr < 4; ++rr) {
        const int row = r0 + rr;
        if (row < M_TOK) dst[(size_t)row * D_DIM + col] = acc[i][j][rr] + bv;
      }
    }
  }
}

// out = sum_s partial[s] + bias  (vectorized float4)
template <int SPLITS>
__global__ __launch_bounds__(256) void k_reduce(const float* __restrict__ padd,
                                                const float* __restrict__ bias,
                                                float* __restrict__ out) {
  int idx = (blockIdx.x * 256 + threadIdx.x) * 4;
  if (idx >= M_TOK * D_DIM) return;
  float4 s = *(const float4*)(bias + (idx % D_DIM));
#pragma unroll
  for (int p = 0; p < SPLITS; ++p) {
    float4 v = *(const float4*)(padd + (size_t)p * M_TOK * D_DIM + idx);
    s.x += v.x; s.y += v.y; s.z += v.z; s.w += v.w;
  }
  *(float4*)(out + idx) = s;
}

// ---------------- launch ----------------

extern "C" void kernel_launch(void* const* d_in, const int* in_sizes, int n_in,
                              void* d_out, int out_size, void* d_ws, size_t ws_size,
                              hipStream_t stream) {
  const float* x     = (const float*)d_in[0];
  const float* W_org = (const float*)d_in[1];
  const float* b_org = (const float*)d_in[2];
  const float* w1    = (const float*)d_in[3];
  const float* b1    = (const float*)d_in[4];
  const float* mid_w = (const float*)d_in[5];
  const float* mid_b = (const float*)d_in[6];
  const float* w_out = (const float*)d_in[7];
  const float* b_out = (const float*)d_in[8];
  float* out = (float*)d_out;

  // workspace carve-up
  bf16* Xb   = (bf16*)d_ws;                         // 4992*768
  bf16* W1t  = Xb  + (size_t)M_PAD * D_DIM;         // 4096*768
  bf16* W2t  = W1t + (size_t)NR * D_DIM;            // 768*4864
  bf16* H2   = W2t + (size_t)D_DIM * K_CAT;         // 4992*4096
  float* bias    = (float*)(H2 + (size_t)M_PAD * NR);
  float* partial = bias + 1024;                     // 32*768 floats
  float* padd    = partial + 32 * D_DIM;            // SPLITS * 4928*768 floats

  const size_t base_bytes = (size_t)((char*)padd - (char*)d_ws);
  const size_t per_split  = (size_t)M_TOK * D_DIM * sizeof(float);
  int S = 1;
  if (ws_size >= base_bytes + 4 * per_split)      S = 4;
  else if (ws_size >= base_bytes + 2 * per_split) S = 2;

  k_prep_x     <<<(M_PAD * D_DIM / 4) / 256, 256, 0, stream>>>(x, Xb);
  k_prep_w1t   <<<(NR * D_DIM / 4) / 256, 256, 0, stream>>>(w1, W1t);
  k_prep_w2t_t <<<64 * 12, 256, 0, stream>>>(w_out, W2t);
  k_prep_w2t_org<<<(D_DIM * D_DIM / 4 + 255) / 256, 256, 0, stream>>>(W_org, W2t);
  k_bias_partial<<<32, 256, 0, stream>>>(b_out, partial);
  k_bias_final  <<<3, 256, 0, stream>>>(partial, b_org, bias);

  k_gemm1<<<39 * 32, 256, 0, stream>>>(Xb, W1t, H2, b1, mid_w, mid_b);

  const int red_grid = (M_TOK * D_DIM / 4 + 255) / 256;
  if (S == 4) {
    k_gemm2<4><<<39 * 6 * 4, 256, 0, stream>>>(H2, Xb, W2t, padd, bias);
    k_reduce<4><<<red_grid, 256, 0, stream>>>(padd, bias, out);
  } else if (S == 2) {
    k_gemm2<2><<<39 * 6 * 2, 256, 0, stream>>>(H2, Xb, W2t, padd, bias);
    k_reduce<2><<<red_grid, 256, 0, stream>>>(padd, bias, out);
  } else {
    k_gemm2<1><<<39 * 6, 256, 0, stream>>>(H2, Xb, W2t, out, bias);
  }
}